// Round 20
// baseline (154.366 us; speedup 1.0000x reference)
//
#include <hip/hip_runtime.h>
#include <hip/hip_bf16.h>

typedef __bf16 bf16_t;
typedef __attribute__((ext_vector_type(8))) __bf16 bf16x8;
typedef __attribute__((ext_vector_type(4))) __bf16 bf16x4;
typedef __attribute__((ext_vector_type(4))) float f32x4;

#define MFMA16(a, b, c) __builtin_amdgcn_mfma_f32_16x16x32_bf16((a), (b), (c), 0, 0, 0)

__device__ __forceinline__ void gload_lds16(const void* g, void* l) {
    __builtin_amdgcn_global_load_lds(
        (const __attribute__((address_space(1))) void*)g,
        (__attribute__((address_space(3))) void*)l, 16, 0, 0);
}

// ---------------------------------------------------------------------------
// Kernel 1: FUSED QKV projection — one X pass, occupancy-restored.
// Tile 64 (M) x 384 (N = Q|K|V), BK = 64, 512 threads (8 waves, 4x2).
// Grid 512 -> 2 blocks/CU (4 waves/SIMD). LDS 56KB. acc 48 regs/thread.
// Q pre-scaled by (1/sqrt(128))*log2(e); V written transposed [b][h][t].
// ---------------------------------------------------------------------------
__global__ __launch_bounds__(512, 2) void proj_qkv(
    const float* __restrict__ X,
    const float* __restrict__ W0, const float* __restrict__ W1, const float* __restrict__ W2,
    bf16_t* __restrict__ O0, bf16_t* __restrict__ O1, bf16_t* __restrict__ O2)
{
    __shared__ __align__(16) char As[64 * 128];    // 64 m-rows x 64 bf16, 8 KB
    __shared__ __align__(16) char Bs[384 * 128];   // 384 n-rows x 64 bf16, 48 KB

    const int tid = threadIdx.x;
    const int wid = tid >> 6;
    const int lane = tid & 63;
    const int l15 = lane & 15, l4 = lane >> 4;
    const int wr = wid >> 1;          // 0..3 : 16 m-rows each
    const int wc = wid & 1;           // 0..1 : 192 n-cols each
    const int m0 = blockIdx.x * 64;

    const int r0 = tid >> 4;          // 0..31
    const int kq = tid & 15;

    f32x4 acc[12] = {};
    float4 xr[2];

    #pragma unroll
    for (int i = 0; i < 2; ++i)
        xr[i] = *(const float4*)(X + (size_t)(m0 + r0 + 32 * i) * 1024 + kq * 4);

    for (int ks = 0; ks < 16; ++ks) {
        const int kb = ks * 64;
        // X slab from prefetch regs -> As
        #pragma unroll
        for (int i = 0; i < 2; ++i) {
            const int r = r0 + 32 * i;
            bf16x4 av; av[0] = (bf16_t)xr[i].x; av[1] = (bf16_t)xr[i].y;
            av[2] = (bf16_t)xr[i].z; av[3] = (bf16_t)xr[i].w;
            *(bf16x4*)(As + r * 128 + ((kq * 8) ^ ((r & 7) << 4))) = av;
        }
        // W slab (L2-hot): rows 0..127 Wq, 128..255 Wk, 256..383 Wv
        #pragma unroll
        for (int i = 0; i < 12; ++i) {
            const int r = r0 + 32 * i;
            const float* Wp = (i < 4) ? W0 : (i < 8 ? W1 : W2);
            const int wrow = r0 + 32 * (i & 3);
            float4 wa = *(const float4*)(Wp + (size_t)wrow * 1024 + kb + kq * 4);
            bf16x4 wv; wv[0] = (bf16_t)wa.x; wv[1] = (bf16_t)wa.y;
            wv[2] = (bf16_t)wa.z; wv[3] = (bf16_t)wa.w;
            *(bf16x4*)(Bs + r * 128 + ((kq * 8) ^ ((r & 7) << 4))) = wv;
        }
        __syncthreads();
        if (ks < 15) {
            #pragma unroll
            for (int i = 0; i < 2; ++i)
                xr[i] = *(const float4*)(X + (size_t)(m0 + r0 + 32 * i) * 1024 + kb + 64 + kq * 4);
        }
        #pragma unroll
        for (int kk = 0; kk < 64; kk += 32) {
            const int kbyte = 2 * kk + 16 * l4;
            bf16x8 af, bfr[12];
            {
                int r = wr * 16 + l15;
                af = *(const bf16x8*)(As + r * 128 + (kbyte ^ ((r & 7) << 4)));
            }
            #pragma unroll
            for (int ni = 0; ni < 12; ++ni) {
                int r = wc * 192 + ni * 16 + l15;
                bfr[ni] = *(const bf16x8*)(Bs + r * 128 + (kbyte ^ ((r & 7) << 4)));
            }
            #pragma unroll
            for (int ni = 0; ni < 12; ++ni)
                acc[ni] = MFMA16(af, bfr[ni], acc[ni]);
        }
        __syncthreads();
    }

    // Epilogue. C/D: col = l15, row = l4*4 + r. qs folds (1/sqrt(128))*log2e.
    const float qs = 0.12751754816f;
    #pragma unroll
    for (int ni = 0; ni < 12; ++ni) {
        const int gcol = 192 * wc + 16 * ni + l15;
        const int sel = gcol >> 7, lc = gcol & 127;
        const int row = m0 + 16 * wr + 4 * l4;
        if (sel == 0) {
            #pragma unroll
            for (int r = 0; r < 4; ++r)
                O0[(size_t)(row + r) * 128 + lc] = (bf16_t)(acc[ni][r] * qs);
        } else if (sel == 1) {
            #pragma unroll
            for (int r = 0; r < 4; ++r)
                O1[(size_t)(row + r) * 128 + lc] = (bf16_t)acc[ni][r];
        } else {
            const int bb = row >> 12, t0 = row & 4095;
            bf16x4 pk;
            #pragma unroll
            for (int r = 0; r < 4; ++r) pk[r] = (bf16_t)acc[ni][r];
            *(bf16x4*)(O2 + ((size_t)bb << 19) + (size_t)lc * 4096 + t0) = pk;
        }
    }
}

// ---------------------------------------------------------------------------
// Kernel 2: causal flash attention (byte-identical r18) — 8-wave blocks,
// 64-q atoms, 64-kv tiles double-buffered, ONE barrier per step, exactly 33
// steps for every block. 256 blocks x 512 threads (1 block/CU, LDS 144KB).
// Waves (qh 0..3, pair 0..1). Base-2 softmax, deferred max, ones-MFMA denom.
// ---------------------------------------------------------------------------
__global__ __launch_bounds__(512, 2) void attn_fwd(
    const bf16_t* __restrict__ Qb, const bf16_t* __restrict__ Kb,
    const bf16_t* __restrict__ Vtg, float* __restrict__ out, int Bn)
{
    // [0,65536): K bufs: pair*32768 + buf*16384. merge: o-dump 4x8KB @ qh*8192.
    // [65536,131072): V bufs. merge: stats @ 65536 + qh*512.
    // [131072,147456): per-wave P (2KB each).
    __shared__ __align__(16) char lds[147456];

    const int tid = threadIdx.x, wid = tid >> 6, lane = tid & 63;
    const int l15 = lane & 15, l4 = lane >> 4;
    const int qh = wid >> 1, pair = wid & 1;

    const int blk = blockIdx.x;
    const int b = blk % Bn;              // batch == XCD -> K/V L2-resident
    const int j = blk / Bn;              // 0..31

    const size_t base = (size_t)b * 4096 * 128;
    const size_t baseVT = (size_t)b << 19;

    char* Pw = lds + 131072 + wid * 2048;
    const int key = l15 & 7;             // 3-bit 16B-chunk XOR key

    bf16x8 aones;
    #pragma unroll
    for (int e = 0; e < 8; ++e) aones[e] = (bf16_t)1.0f;

    for (int seg = 0; seg < 2; ++seg) {
        const int p = seg ? (63 - j) : j;      // 64q atom
        const int q0 = p << 6;
        const int T = p + 1;                   // 64-kv tiles in atom
        const int smax = (T + 1) >> 1;         // pair-0 steps (>= pair-1)
        const int qg = q0 + 16 * qh + l15;     // this lane's q row

        bf16x8 aq[4];
        #pragma unroll
        for (int kf = 0; kf < 4; ++kf)
            aq[kf] = *(const bf16x8*)(Qb + base + (size_t)qg * 128 + 32 * kf + 8 * l4);

        float mx = -1e30f;
        f32x4 ls_acc = (f32x4){0.f, 0.f, 0.f, 0.f};
        f32x4 o[8] = {};

        auto stage = [&](int s) {
            const int lt = 2 * s + pair;
            if (lt >= T) return;
            const int kv0 = lt << 6;
            if (qh < 2) {
                char* Kd = lds + pair * 32768 + (s & 1) * 16384;
                #pragma unroll
                for (int c = 0; c < 8; ++c) {
                    const int it = qh * 8 + c;
                    const int row = it * 4 + (lane >> 4);
                    const bf16_t* src = Kb + base + (size_t)(kv0 + row) * 128
                                        + (((lane & 15) ^ (row & 7)) << 3);
                    gload_lds16(src, Kd + it * 1024);
                }
            } else {
                char* Vd = lds + 65536 + pair * 32768 + (s & 1) * 16384;
                #pragma unroll
                for (int c = 0; c < 8; ++c) {
                    const int it = (qh - 2) * 8 + c;
                    const int h = it * 8 + (lane >> 3);
                    const bf16_t* src = Vtg + baseVT + (size_t)h * 4096 + kv0
                                        + (((lane & 7) ^ ((lane >> 3) & 7)) << 3);
                    gload_lds16(src, Vd + it * 1024);
                }
            }
        };

        __syncthreads();
        stage(0);
        __syncthreads();

        for (int s = 0; s < smax; ++s) {
            if (s + 1 < smax) stage(s + 1);    // issue FIRST: hidden under compute
            const int lt = 2 * s + pair;
            if (lt < T) {
                const int kv0 = lt << 6;
                char* Kbuf = lds + pair * 32768 + (s & 1) * 16384;
                char* Vbuf = lds + 65536 + pair * 32768 + (s & 1) * 16384;

                f32x4 sa[4];
                #pragma unroll
                for (int ni = 0; ni < 4; ++ni) sa[ni] = (f32x4){0.f, 0.f, 0.f, 0.f};
                __builtin_amdgcn_s_setprio(1);
                #pragma unroll
                for (int kf = 0; kf < 4; ++kf)
                    #pragma unroll
                    for (int ni = 0; ni < 4; ++ni) {
                        bf16x8 ak = *(const bf16x8*)(Kbuf + (16 * ni + l15) * 256
                                                     + (((4 * kf + l4) ^ key) << 4));
                        sa[ni] = MFMA16(ak, aq[kf], sa[ni]);
                    }
                __builtin_amdgcn_s_setprio(0);

                if (lt == T - 1) {
                    #pragma unroll
                    for (int ni = 0; ni < 4; ++ni)
                        #pragma unroll
                        for (int r = 0; r < 4; ++r)
                            if (kv0 + 16 * ni + 4 * l4 + r > qg) sa[ni][r] = -1e30f;
                }

                float tm = -1e30f;
                #pragma unroll
                for (int ni = 0; ni < 4; ++ni)
                    tm = fmaxf(tm, fmaxf(fmaxf(sa[ni][0], sa[ni][1]),
                                         fmaxf(sa[ni][2], sa[ni][3])));
                if (__any(tm > mx + 8.0f)) {
                    tm = fmaxf(tm, __shfl_xor(tm, 16, 64));
                    tm = fmaxf(tm, __shfl_xor(tm, 32, 64));
                    const float mnew = fmaxf(mx, tm);
                    const float c = exp2f(mx - mnew);
                    ls_acc[0] *= c; ls_acc[1] *= c; ls_acc[2] *= c; ls_acc[3] *= c;
                    #pragma unroll
                    for (int mf = 0; mf < 8; ++mf) {
                        f32x4 t = o[mf];
                        t[0] *= c; t[1] *= c; t[2] *= c; t[3] *= c;
                        o[mf] = t;
                    }
                    mx = mnew;
                }
                #pragma unroll
                for (int ni = 0; ni < 4; ++ni) {
                    bf16x4 pv;
                    #pragma unroll
                    for (int r = 0; r < 4; ++r)
                        pv[r] = (bf16_t)exp2f(sa[ni][r] - mx);
                    *(bf16x4*)(Pw + l15 * 128
                               + (((2 * ni + (l4 >> 1)) ^ key) << 4) + 8 * (l4 & 1)) = pv;
                }

                __builtin_amdgcn_s_setprio(1);
                #pragma unroll
                for (int kfp = 0; kfp < 2; ++kfp) {
                    const int cb = ((4 * kfp + l4) ^ key) << 4;
                    bf16x8 pb = *(const bf16x8*)(Pw + l15 * 128 + cb);
                    ls_acc = MFMA16(aones, pb, ls_acc);
                    #pragma unroll
                    for (int mf = 0; mf < 8; ++mf) {
                        bf16x8 av = *(const bf16x8*)(Vbuf + (16 * mf + l15) * 128 + cb);
                        o[mf] = MFMA16(av, pb, o[mf]);
                    }
                }
                __builtin_amdgcn_s_setprio(0);
            }
            __syncthreads();
        }

        // ---- 2-way kv-merge (pair 1 -> pair 0), then store ----
        if (pair == 1) {
            char* dst = lds + qh * 8192;
            #pragma unroll
            for (int mf = 0; mf < 8; ++mf)
                *(f32x4*)(dst + mf * 1024 + lane * 16) = o[mf];
            *(float2*)(lds + 65536 + qh * 512 + lane * 8) = make_float2(mx, ls_acc[0]);
        }
        __syncthreads();
        if (pair == 0) {
            float2 st = *(const float2*)(lds + 65536 + qh * 512 + lane * 8);
            const float mB = st.x, lB = st.y;
            const float M = fmaxf(mx, mB);
            const float a = exp2f(mx - M), b2 = exp2f(mB - M);
            const float linv = 1.f / (ls_acc[0] * a + lB * b2);
            char* srcO = lds + qh * 8192;
            float* op = out + ((size_t)b * 4096 + qg) * 128 + 4 * l4;
            #pragma unroll
            for (int mf = 0; mf < 8; ++mf) {
                f32x4 ob = *(const f32x4*)(srcO + mf * 1024 + lane * 16);
                f32x4 r;
                #pragma unroll
                for (int e = 0; e < 4; ++e) r[e] = (o[mf][e] * a + ob[e] * b2) * linv;
                *(f32x4*)(op + 16 * mf) = r;
            }
        }
    }
}

extern "C" void kernel_launch(void* const* d_in, const int* in_sizes, int n_in,
                              void* d_out, int out_size, void* d_ws, size_t ws_size,
                              hipStream_t stream) {
    const float* X  = (const float*)d_in[0];
    const float* Wq = (const float*)d_in[1];
    const float* Wk = (const float*)d_in[2];
    const float* Wv = (const float*)d_in[3];
    float* out = (float*)d_out;

    const int M = in_sizes[0] / 1024;      // B*T = 32768
    const int Bn = M / 4096;               // 8

    bf16_t* Qb  = (bf16_t*)d_ws;
    bf16_t* KbP = Qb + (size_t)M * 128;
    bf16_t* VtP = KbP + (size_t)M * 128;   // transposed: [b][128][4096]

    proj_qkv<<<dim3(M / 64), 512, 0, stream>>>(X, Wq, Wk, Wv, Qb, KbP, VtP);
    attn_fwd<<<dim3(32 * Bn), 512, 0, stream>>>(Qb, KbP, VtP, out, Bn);
}

// Round 21
// 115.958 us; speedup vs baseline: 1.3312x; 1.3312x over previous
//
#include <hip/hip_runtime.h>
#include <hip/hip_bf16.h>

typedef __bf16 bf16_t;
typedef __attribute__((ext_vector_type(8))) __bf16 bf16x8;
typedef __attribute__((ext_vector_type(4))) __bf16 bf16x4;
typedef __attribute__((ext_vector_type(4))) float f32x4;

#define MFMA16(a, b, c) __builtin_amdgcn_mfma_f32_16x16x32_bf16((a), (b), (c), 0, 0, 0)

__device__ __forceinline__ void gload_lds16(const void* g, void* l) {
    __builtin_amdgcn_global_load_lds(
        (const __attribute__((address_space(1))) void*)g,
        (__attribute__((address_space(3))) void*)l, 16, 0, 0);
}

// ---------------------------------------------------------------------------
// Kernel 0: one-shot W fp32 -> bf16 conversion (3 x 128 x 1024 = 0.75 MB out).
// ---------------------------------------------------------------------------
__global__ __launch_bounds__(256) void conv_w(
    const float* __restrict__ W0, const float* __restrict__ W1,
    const float* __restrict__ W2, bf16_t* __restrict__ Wb)
{
    const int idx = blockIdx.x * 256 + threadIdx.x;       // 0..98303 (x4 elems)
    const float* src = (idx < 32768) ? W0 : (idx < 65536) ? W1 : W2;
    const int off = (idx & 32767) * 4;
    float4 v = *(const float4*)(src + off);
    bf16x4 o; o[0] = (bf16_t)v.x; o[1] = (bf16_t)v.y;
    o[2] = (bf16_t)v.z; o[3] = (bf16_t)v.w;
    *(bf16x4*)(Wb + (size_t)idx * 4) = o;
}

// ---------------------------------------------------------------------------
// Kernel 1: QKV projection (r18 3-pass structure), W staged from bf16.
// Tile 128x128, BK=64, 256 thr, X slab reg-prefetched, 3 waves/SIMD.
// Q pre-scaled by (1/sqrt(128))*log2e; V written transposed [b][h][t].
// ---------------------------------------------------------------------------
__global__ __launch_bounds__(256, 3) void proj_qkv(
    const float* __restrict__ X, const bf16_t* __restrict__ Wb,
    bf16_t* __restrict__ O0, bf16_t* __restrict__ O1, bf16_t* __restrict__ O2)
{
    __shared__ __align__(16) char As[128 * 128];
    __shared__ __align__(16) char Bs[128 * 128];

    const int tid = threadIdx.x;
    const int wid = tid >> 6;
    const int lane = tid & 63;
    const int l15 = lane & 15, l4 = lane >> 4;
    const int wr = wid >> 1, wc = wid & 1;
    const int m0 = blockIdx.x * 128;

    const bf16_t* Wp = Wb + (size_t)blockIdx.y * 131072;  // 128 x 1024 bf16

    const int r0 = tid >> 4;
    const int kq = tid & 15;
    const int swz = ((r0 & 7) << 4);

    f32x4 acc[4][4] = {};
    float4 xr[8];

    #pragma unroll
    for (int i = 0; i < 8; ++i)
        xr[i] = *(const float4*)(X + (size_t)(m0 + r0 + i * 16) * 1024 + kq * 4);

    for (int ks = 0; ks < 16; ++ks) {
        const int kb = ks * 64;
        // X slab from prefetch regs -> As (fp32 -> bf16)
        #pragma unroll
        for (int i = 0; i < 8; ++i) {
            const int r = r0 + i * 16;
            bf16x4 av; av[0] = (bf16_t)xr[i].x; av[1] = (bf16_t)xr[i].y;
            av[2] = (bf16_t)xr[i].z; av[3] = (bf16_t)xr[i].w;
            *(bf16x4*)(As + r * 128 + ((kq * 8) ^ swz)) = av;
        }
        // W slab from bf16 (L2-hot): 4 x b128 load+store per thread.
        #pragma unroll
        for (int i = 0; i < 4; ++i) {
            const int c = i * 256 + tid;       // 0..1023 16B-chunks
            const int row = c >> 3, ch = c & 7;
            bf16x8 wv = *(const bf16x8*)(Wp + (size_t)row * 1024 + kb + ch * 8);
            *(bf16x8*)(Bs + row * 128 + ((ch ^ (row & 7)) << 4)) = wv;
        }
        __syncthreads();
        if (ks < 15) {
            #pragma unroll
            for (int i = 0; i < 8; ++i)
                xr[i] = *(const float4*)(X + (size_t)(m0 + r0 + i * 16) * 1024 + kb + 64 + kq * 4);
        }
        #pragma unroll
        for (int kk = 0; kk < 64; kk += 32) {
            const int kbyte = 2 * kk + 16 * l4;
            bf16x8 af[4], bfr[4];
            #pragma unroll
            for (int mi = 0; mi < 4; ++mi) {
                int r = wr * 64 + mi * 16 + l15;
                af[mi] = *(const bf16x8*)(As + r * 128 + (kbyte ^ ((r & 7) << 4)));
            }
            #pragma unroll
            for (int ni = 0; ni < 4; ++ni) {
                int r = wc * 64 + ni * 16 + l15;
                bfr[ni] = *(const bf16x8*)(Bs + r * 128 + (kbyte ^ ((r & 7) << 4)));
            }
            #pragma unroll
            for (int mi = 0; mi < 4; ++mi)
                #pragma unroll
                for (int ni = 0; ni < 4; ++ni)
                    acc[mi][ni] = MFMA16(af[mi], bfr[ni], acc[mi][ni]);
        }
        __syncthreads();
    }

    if (blockIdx.y < 2) {
        const float sc = (blockIdx.y == 0) ? 0.12751754816f : 1.0f;  // 1/sqrt(128)*log2e
        bf16_t* O = (blockIdx.y == 0) ? O0 : O1;
        #pragma unroll
        for (int mi = 0; mi < 4; ++mi)
            #pragma unroll
            for (int ni = 0; ni < 4; ++ni) {
                int row = m0 + wr * 64 + mi * 16 + l4 * 4;
                int col = wc * 64 + ni * 16 + l15;
                #pragma unroll
                for (int r = 0; r < 4; ++r)
                    O[(size_t)(row + r) * 128 + col] = (bf16_t)(acc[mi][ni][r] * sc);
            }
    } else {
        #pragma unroll
        for (int mi = 0; mi < 4; ++mi)
            #pragma unroll
            for (int ni = 0; ni < 4; ++ni) {
                int row0 = m0 + wr * 64 + mi * 16 + l4 * 4;
                int col = wc * 64 + ni * 16 + l15;
                int bb = row0 >> 12, t0 = row0 & 4095;
                bf16x4 pk;
                #pragma unroll
                for (int r = 0; r < 4; ++r) pk[r] = (bf16_t)acc[mi][ni][r];
                *(bf16x4*)(O2 + ((size_t)bb << 19) + (size_t)col * 4096 + t0) = pk;
            }
    }
}

// ---------------------------------------------------------------------------
// Kernel 2: causal flash attention (byte-identical r18) — 8-wave blocks,
// 64-q atoms, 64-kv tiles double-buffered, ONE barrier per step, exactly 33
// steps for every block. 256 blocks x 512 threads (1 block/CU, LDS 144KB).
// Waves (qh 0..3, pair 0..1). Base-2 softmax, deferred max, ones-MFMA denom.
// ---------------------------------------------------------------------------
__global__ __launch_bounds__(512, 2) void attn_fwd(
    const bf16_t* __restrict__ Qb, const bf16_t* __restrict__ Kb,
    const bf16_t* __restrict__ Vtg, float* __restrict__ out, int Bn)
{
    // [0,65536): K bufs: pair*32768 + buf*16384. merge: o-dump 4x8KB @ qh*8192.
    // [65536,131072): V bufs. merge: stats @ 65536 + qh*512.
    // [131072,147456): per-wave P (2KB each).
    __shared__ __align__(16) char lds[147456];

    const int tid = threadIdx.x, wid = tid >> 6, lane = tid & 63;
    const int l15 = lane & 15, l4 = lane >> 4;
    const int qh = wid >> 1, pair = wid & 1;

    const int blk = blockIdx.x;
    const int b = blk % Bn;              // batch == XCD -> K/V L2-resident
    const int j = blk / Bn;              // 0..31

    const size_t base = (size_t)b * 4096 * 128;
    const size_t baseVT = (size_t)b << 19;

    char* Pw = lds + 131072 + wid * 2048;
    const int key = l15 & 7;             // 3-bit 16B-chunk XOR key

    bf16x8 aones;
    #pragma unroll
    for (int e = 0; e < 8; ++e) aones[e] = (bf16_t)1.0f;

    for (int seg = 0; seg < 2; ++seg) {
        const int p = seg ? (63 - j) : j;      // 64q atom
        const int q0 = p << 6;
        const int T = p + 1;                   // 64-kv tiles in atom
        const int smax = (T + 1) >> 1;         // pair-0 steps (>= pair-1)
        const int qg = q0 + 16 * qh + l15;     // this lane's q row

        bf16x8 aq[4];
        #pragma unroll
        for (int kf = 0; kf < 4; ++kf)
            aq[kf] = *(const bf16x8*)(Qb + base + (size_t)qg * 128 + 32 * kf + 8 * l4);

        float mx = -1e30f;
        f32x4 ls_acc = (f32x4){0.f, 0.f, 0.f, 0.f};
        f32x4 o[8] = {};

        auto stage = [&](int s) {
            const int lt = 2 * s + pair;
            if (lt >= T) return;
            const int kv0 = lt << 6;
            if (qh < 2) {
                char* Kd = lds + pair * 32768 + (s & 1) * 16384;
                #pragma unroll
                for (int c = 0; c < 8; ++c) {
                    const int it = qh * 8 + c;
                    const int row = it * 4 + (lane >> 4);
                    const bf16_t* src = Kb + base + (size_t)(kv0 + row) * 128
                                        + (((lane & 15) ^ (row & 7)) << 3);
                    gload_lds16(src, Kd + it * 1024);
                }
            } else {
                char* Vd = lds + 65536 + pair * 32768 + (s & 1) * 16384;
                #pragma unroll
                for (int c = 0; c < 8; ++c) {
                    const int it = (qh - 2) * 8 + c;
                    const int h = it * 8 + (lane >> 3);
                    const bf16_t* src = Vtg + baseVT + (size_t)h * 4096 + kv0
                                        + (((lane & 7) ^ ((lane >> 3) & 7)) << 3);
                    gload_lds16(src, Vd + it * 1024);
                }
            }
        };

        __syncthreads();
        stage(0);
        __syncthreads();

        for (int s = 0; s < smax; ++s) {
            if (s + 1 < smax) stage(s + 1);    // issue FIRST: hidden under compute
            const int lt = 2 * s + pair;
            if (lt < T) {
                const int kv0 = lt << 6;
                char* Kbuf = lds + pair * 32768 + (s & 1) * 16384;
                char* Vbuf = lds + 65536 + pair * 32768 + (s & 1) * 16384;

                f32x4 sa[4];
                #pragma unroll
                for (int ni = 0; ni < 4; ++ni) sa[ni] = (f32x4){0.f, 0.f, 0.f, 0.f};
                __builtin_amdgcn_s_setprio(1);
                #pragma unroll
                for (int kf = 0; kf < 4; ++kf)
                    #pragma unroll
                    for (int ni = 0; ni < 4; ++ni) {
                        bf16x8 ak = *(const bf16x8*)(Kbuf + (16 * ni + l15) * 256
                                                     + (((4 * kf + l4) ^ key) << 4));
                        sa[ni] = MFMA16(ak, aq[kf], sa[ni]);
                    }
                __builtin_amdgcn_s_setprio(0);

                if (lt == T - 1) {
                    #pragma unroll
                    for (int ni = 0; ni < 4; ++ni)
                        #pragma unroll
                        for (int r = 0; r < 4; ++r)
                            if (kv0 + 16 * ni + 4 * l4 + r > qg) sa[ni][r] = -1e30f;
                }

                float tm = -1e30f;
                #pragma unroll
                for (int ni = 0; ni < 4; ++ni)
                    tm = fmaxf(tm, fmaxf(fmaxf(sa[ni][0], sa[ni][1]),
                                         fmaxf(sa[ni][2], sa[ni][3])));
                if (__any(tm > mx + 8.0f)) {
                    tm = fmaxf(tm, __shfl_xor(tm, 16, 64));
                    tm = fmaxf(tm, __shfl_xor(tm, 32, 64));
                    const float mnew = fmaxf(mx, tm);
                    const float c = exp2f(mx - mnew);
                    ls_acc[0] *= c; ls_acc[1] *= c; ls_acc[2] *= c; ls_acc[3] *= c;
                    #pragma unroll
                    for (int mf = 0; mf < 8; ++mf) {
                        f32x4 t = o[mf];
                        t[0] *= c; t[1] *= c; t[2] *= c; t[3] *= c;
                        o[mf] = t;
                    }
                    mx = mnew;
                }
                #pragma unroll
                for (int ni = 0; ni < 4; ++ni) {
                    bf16x4 pv;
                    #pragma unroll
                    for (int r = 0; r < 4; ++r)
                        pv[r] = (bf16_t)exp2f(sa[ni][r] - mx);
                    *(bf16x4*)(Pw + l15 * 128
                               + (((2 * ni + (l4 >> 1)) ^ key) << 4) + 8 * (l4 & 1)) = pv;
                }

                __builtin_amdgcn_s_setprio(1);
                #pragma unroll
                for (int kfp = 0; kfp < 2; ++kfp) {
                    const int cb = ((4 * kfp + l4) ^ key) << 4;
                    bf16x8 pb = *(const bf16x8*)(Pw + l15 * 128 + cb);
                    ls_acc = MFMA16(aones, pb, ls_acc);
                    #pragma unroll
                    for (int mf = 0; mf < 8; ++mf) {
                        bf16x8 av = *(const bf16x8*)(Vbuf + (16 * mf + l15) * 128 + cb);
                        o[mf] = MFMA16(av, pb, o[mf]);
                    }
                }
                __builtin_amdgcn_s_setprio(0);
            }
            __syncthreads();
        }

        // ---- 2-way kv-merge (pair 1 -> pair 0), then store ----
        if (pair == 1) {
            char* dst = lds + qh * 8192;
            #pragma unroll
            for (int mf = 0; mf < 8; ++mf)
                *(f32x4*)(dst + mf * 1024 + lane * 16) = o[mf];
            *(float2*)(lds + 65536 + qh * 512 + lane * 8) = make_float2(mx, ls_acc[0]);
        }
        __syncthreads();
        if (pair == 0) {
            float2 st = *(const float2*)(lds + 65536 + qh * 512 + lane * 8);
            const float mB = st.x, lB = st.y;
            const float M = fmaxf(mx, mB);
            const float a = exp2f(mx - M), b2 = exp2f(mB - M);
            const float linv = 1.f / (ls_acc[0] * a + lB * b2);
            char* srcO = lds + qh * 8192;
            float* op = out + ((size_t)b * 4096 + qg) * 128 + 4 * l4;
            #pragma unroll
            for (int mf = 0; mf < 8; ++mf) {
                f32x4 ob = *(const f32x4*)(srcO + mf * 1024 + lane * 16);
                f32x4 r;
                #pragma unroll
                for (int e = 0; e < 4; ++e) r[e] = (o[mf][e] * a + ob[e] * b2) * linv;
                *(f32x4*)(op + 16 * mf) = r;
            }
        }
    }
}

extern "C" void kernel_launch(void* const* d_in, const int* in_sizes, int n_in,
                              void* d_out, int out_size, void* d_ws, size_t ws_size,
                              hipStream_t stream) {
    const float* X  = (const float*)d_in[0];
    const float* Wq = (const float*)d_in[1];
    const float* Wk = (const float*)d_in[2];
    const float* Wv = (const float*)d_in[3];
    float* out = (float*)d_out;

    const int M = in_sizes[0] / 1024;      // B*T = 32768
    const int Bn = M / 4096;               // 8

    bf16_t* Qb  = (bf16_t*)d_ws;
    bf16_t* KbP = Qb + (size_t)M * 128;
    bf16_t* VtP = KbP + (size_t)M * 128;   // transposed: [b][128][4096]
    bf16_t* Wb  = VtP + (size_t)M * 128;   // 3 x 128 x 1024 bf16

    conv_w<<<dim3(384), 256, 0, stream>>>(Wq, Wk, Wv, Wb);
    proj_qkv<<<dim3(M / 128, 3), 256, 0, stream>>>(X, Wb, Qb, KbP, VtP);
    attn_fwd<<<dim3(32 * Bn), 512, 0, stream>>>(Qb, KbP, VtP, out, Bn);
}